// Round 13
// baseline (53.455 us; speedup 1.0000x reference)
//
#include <hip/hip_runtime.h>
#include <hip/hip_bf16.h>
#include <stdint.h>

#define N_HEADS 16
#define HEAD_DIM 64
#define SEQ_LEN 2048
#define KVBLK 64                    // two verified 32-row sub-blocks per iter
#define NT 16                       // iterations per half-stream
#define NTILE_TOT (SEQ_LEN / 32)    // 32-row image tiles

typedef __bf16 bf16x8 __attribute__((ext_vector_type(8)));
typedef __bf16 bf16x4 __attribute__((ext_vector_type(4)));
typedef short  s16x4  __attribute__((ext_vector_type(4)));
typedef float  f32x4  __attribute__((ext_vector_type(4)));
typedef unsigned int u32x4 __attribute__((ext_vector_type(4)));

#if __has_builtin(__builtin_amdgcn_mfma_f32_16x16x16bf16_1k)
#define HAVE_MFMA16 1
#else
#define HAVE_MFMA16 0
#endif

static __device__ __forceinline__ unsigned pkbf(float a, float b) {
    union { __bf16 h[2]; unsigned u; } t;
    t.h[0] = (__bf16)a; t.h[1] = (__bf16)b;
    return t.u;
}

// Prep: swizzled bf16 images of K (row-major) and Vt (transposed), one 4 KB
// block per (head, 32-row tile) — byte-exact replicas of the verified LDS
// tiles (identical write formulas, executed once instead of 32x/head).
//   K : row-major bf16 [32][64], addr = row*128 + (off ^ ((row&7)<<4))
//   Vt: transposed bf16, FULL-ADDRESS XOR: addr = (vc*64 + off) ^ ((vc&7)<<4)
__global__ __launch_bounds__(256)
void prep_kernel(const float* __restrict__ k,
                 const float* __restrict__ v,
                 char* __restrict__ kimg,
                 char* __restrict__ vtimg) {
    const int ts  = blockIdx.x;         // 32-row tile 0..63
    const int h   = blockIdx.y;
    const int tid = threadIdx.x;
    const int s0  = ts * 32;
    const size_t blk = ((size_t)h * NTILE_TOT + ts) * 4096;

    const int krow = tid >> 3;
    const int kcol = (tid & 7) * 8;
    const float* ks = k + ((size_t)h * SEQ_LEN + s0 + krow) * HEAD_DIM + kcol;
    f32x4 a = *(const f32x4*)ks;
    f32x4 b = *(const f32x4*)(ks + 4);
    bf16x8 kb;
    #pragma unroll
    for (int i = 0; i < 4; ++i) { kb[i] = (__bf16)a[i]; kb[4 + i] = (__bf16)b[i]; }
    *(bf16x8*)(kimg + blk + krow * 128 + ((kcol * 2) ^ ((krow & 7) << 4))) = kb;

    const int vc = tid & 63;
    const int vr = (tid >> 6) * 8;
    const float* vs = v + ((size_t)h * SEQ_LEN + s0 + vr) * HEAD_DIM + vc;
    bf16x8 vb;
    #pragma unroll
    for (int j = 0; j < 8; ++j) vb[j] = (__bf16)vs[(size_t)j * HEAD_DIM];
    *(bf16x8*)(vtimg + blk + (((vc * 64) + (vr * 2)) ^ ((vc & 7) << 4))) = vb;
}

// 8-wave WG, 2-way intra-WG KV split, KVBLK=64 (2 verified 32-row sub-blocks).
// IMG=true: K-fragments load DIRECTLY from the pre-swizzled global image
// (L1/L2-hot, same offset formula as the old LDS read) — K never touches LDS.
// Only Vt is LDS-staged (dbuf, verbatim 16B copies). DS pipe per wave-iter
// ~264 -> ~144 cyc (it was ~80% busy incl. conflicts - R11 model).
// Defer-rescale (T13, THR=8 base-2). Zero-shuffle PV via K=16 MFMA.
// LDS IMG: 32 KiB = Vt [half][dbuf][2 sub][4096]; merge overlays after loop.
template <bool IMG>
__global__ __launch_bounds__(512, 2)
void attn_alibi_kernel(const float* __restrict__ q,
                       const float* __restrict__ k,
                       const float* __restrict__ v,
                       float* __restrict__ out,
                       const char* __restrict__ kimg,
                       const char* __restrict__ vtimg) {
    const int tid  = threadIdx.x;
    const int wave = tid >> 6;
    const int lane = tid & 63;
    const int col  = lane & 15;
    const int g    = lane >> 4;
    const int half = wave >> 2;
    const int w4   = wave & 3;

    const int h      = blockIdx.y;
    const int qbase  = blockIdx.x * 64 + w4 * 16;
    const int kstart = half * (NT * KVBLK);

    const float* qh = q + (size_t)h * SEQ_LEN * HEAD_DIM;
    const float* kh = k + (size_t)h * SEQ_LEN * HEAD_DIM;
    const float* vh = v + (size_t)h * SEQ_LEN * HEAD_DIM;

    constexpr int SMEM = IMG ? 32768 : 65536;
    __shared__ alignas(16) char smem[SMEM];
    char* kbase  = IMG ? nullptr : smem + half * 16384;
    char* vtbase = IMG ? (smem + half * 16384) : (smem + 32768 + half * 16384);

    const float LOG2E  = 1.4426950408889634f;
    const float scale2 = 0.125f * LOG2E;
    const float slope  = exp2f(-0.5f * (float)(h + 1));
    const float slope2 = slope * LOG2E;

    // ---- Q B-fragments: lane holds Q[qbase+col][c*32 + g*8 + b] ----
    bf16x8 qf[2];
    {
        const float* qr = qh + (size_t)(qbase + col) * HEAD_DIM + g * 8;
        #pragma unroll
        for (int c = 0; c < 2; ++c)
            #pragma unroll
            for (int b = 0; b < 8; ++b) qf[c][b] = (__bf16)qr[c * 32 + b];
    }

    // ALiBi: cb[i] covers k-local i*16+g*4+r, i=0..3 over the 64-row tile
    float cb[4][4];
    #pragma unroll
    for (int i = 0; i < 4; ++i)
        #pragma unroll
        for (int r = 0; r < 4; ++r)
            cb[i][r] = slope2 * (float)(i * 16 + g * 4 + r - (qbase + col));

    float m = -1e30f, l = 0.0f;
    f32x4 acc[4];
    #pragma unroll
    for (int dt = 0; dt < 4; ++dt) acc[dt] = (f32x4)0.0f;

    // ---- staging / K-image setup ----
    const int hid  = tid & 255;
    const int krow = hid >> 3;
    const int kcol = (hid & 7) * 8;
    const int vc   = hid & 63;
    const int vr   = (hid >> 6) * 8;

    // K-image per-lane read offsets (same formula as the old LDS read):
    const int swzK = (col & 7) << 4;
    const int ko0  = (g * 16) ^ swzK;
    const int ko1  = (64 + g * 16) ^ swzK;
    const char* kih = nullptr;      // IMG: this half's K image + row base
    const char* vis = nullptr;
    const float* ksrc = nullptr; const float* vsrc = nullptr;
    char* kdst = nullptr; char* vtdst = nullptr;
    if constexpr (IMG) {
        const size_t hbase = ((size_t)h * NTILE_TOT + half * (NTILE_TOT / 2)) * 4096;
        kih   = kimg + hbase + col * 128;
        vis   = vtimg + hbase + hid * 16;
        vtdst = vtbase + hid * 16;
    } else {
        ksrc  = kh + (size_t)(kstart + krow) * HEAD_DIM + kcol;
        kdst  = kbase + krow * 128 + ((kcol * 2) ^ ((krow & 7) << 4));
        vsrc  = vh + (size_t)(kstart + vr) * HEAD_DIM + vc;
        vtdst = vtbase + (((vc * 64) + (vr * 2)) ^ ((vc & 7) << 4));
    }

    f32x4 vreg[2];                   // IMG: raw 16B Vt chunks per sub-block
    f32x4 kr[2][2];                  // direct path
    float vv[2][8];

    // ---- prologue: stage iteration 0 into buf 0 ----
    if constexpr (IMG) {
        #pragma unroll
        for (int sb = 0; sb < 2; ++sb) {
            vreg[sb] = *(const f32x4*)(vis + sb * 4096);
            *(f32x4*)(vtdst + sb * 4096) = vreg[sb];
        }
    } else {
        #pragma unroll
        for (int sb = 0; sb < 2; ++sb) {
            const float* ks = ksrc + (size_t)(sb * 32) * HEAD_DIM;
            const float* vs = vsrc + (size_t)(sb * 32) * HEAD_DIM;
            kr[sb][0] = *(const f32x4*)(ks);
            kr[sb][1] = *(const f32x4*)(ks + 4);
            #pragma unroll
            for (int j = 0; j < 8; ++j) vv[sb][j] = vs[(size_t)j * HEAD_DIM];
            bf16x8 kb16, vb16;
            #pragma unroll
            for (int b = 0; b < 4; ++b) { kb16[b] = (__bf16)kr[sb][0][b]; kb16[4 + b] = (__bf16)kr[sb][1][b]; }
            #pragma unroll
            for (int j = 0; j < 8; ++j) vb16[j] = (__bf16)vv[sb][j];
            *(bf16x8*)(kdst  + sb * 4096) = kb16;
            *(bf16x8*)(vtdst + sb * 4096) = vb16;
        }
    }
    __syncthreads();

    for (int t = 0; t < NT; ++t) {
        const int kb  = kstart + t * KVBLK;
        const int buf = t & 1;
        const char* vtbuf = vtbase + buf * 8192;

        // ---- S^T = K Q^T over 64 k-rows ----
        f32x4 sacc[4];
        #pragma unroll
        for (int i = 0; i < 4; ++i) sacc[i] = (f32x4)0.0f;

        if constexpr (IMG) {
            // K-frags directly from the pre-swizzled image (global, L1/L2-hot)
            bf16x8 kf[2][2][2];
            #pragma unroll
            for (int sb = 0; sb < 2; ++sb) {
                const char* kp = kih + (size_t)(t * 2 + sb) * 4096;
                #pragma unroll
                for (int jt = 0; jt < 2; ++jt) {
                    kf[sb][jt][0] = *(const bf16x8*)(kp + jt * 2048 + ko0);
                    kf[sb][jt][1] = *(const bf16x8*)(kp + jt * 2048 + ko1);
                }
            }
            #pragma unroll
            for (int sb = 0; sb < 2; ++sb)
                #pragma unroll
                for (int jt = 0; jt < 2; ++jt) {
                    const int i = sb * 2 + jt;
                    sacc[i] = __builtin_amdgcn_mfma_f32_16x16x32_bf16(kf[sb][jt][0], qf[0], sacc[i], 0, 0, 0);
                    sacc[i] = __builtin_amdgcn_mfma_f32_16x16x32_bf16(kf[sb][jt][1], qf[1], sacc[i], 0, 0, 0);
                }
        } else {
            const char* kbuf = kbase + buf * 8192;
            #pragma unroll
            for (int sb = 0; sb < 2; ++sb)
                #pragma unroll
                for (int jt = 0; jt < 2; ++jt) {
                    const int row = jt * 16 + col;
                    const int i   = sb * 2 + jt;
                    #pragma unroll
                    for (int c = 0; c < 2; ++c) {
                        bf16x8 kf = *(const bf16x8*)(kbuf + sb * 4096 + row * 128
                                                     + ((c * 64 + g * 16) ^ ((row & 7) << 4)));
                        sacc[i] = __builtin_amdgcn_mfma_f32_16x16x32_bf16(kf, qf[c], sacc[i], 0, 0, 0);
                    }
                }
        }

        // ---- issue next-iteration V staging loads ----
        if (t + 1 < NT) {
            if constexpr (IMG) {
                #pragma unroll
                for (int sb = 0; sb < 2; ++sb)
                    vreg[sb] = *(const f32x4*)(vis + (size_t)((t + 1) * 2 + sb) * 4096);
            } else {
                #pragma unroll
                for (int sb = 0; sb < 2; ++sb) {
                    const float* ks = ksrc + (size_t)((t + 1) * 64 + sb * 32) * HEAD_DIM;
                    const float* vs = vsrc + (size_t)((t + 1) * 64 + sb * 32) * HEAD_DIM;
                    kr[sb][0] = *(const f32x4*)(ks);
                    kr[sb][1] = *(const f32x4*)(ks + 4);
                    #pragma unroll
                    for (int j = 0; j < 8; ++j) vv[sb][j] = vs[(size_t)j * HEAD_DIM];
                }
            }
        }

        // ---- scale + alibi (base-2) ----
        const float skb = slope2 * (float)kb;
        float s[4][4];
        #pragma unroll
        for (int i = 0; i < 4; ++i)
            #pragma unroll
            for (int r = 0; r < 4; ++r)
                s[i][r] = sacc[i][r] * scale2 + (cb[i][r] + skb);

        // ---- tile max over 64 kv (tree + 2 shfl across g-groups) ----
        float x01a = fmaxf(s[0][0], s[0][1]), x01b = fmaxf(s[0][2], s[0][3]);
        float x23a = fmaxf(s[1][0], s[1][1]), x23b = fmaxf(s[1][2], s[1][3]);
        float x45a = fmaxf(s[2][0], s[2][1]), x45b = fmaxf(s[2][2], s[2][3]);
        float x67a = fmaxf(s[3][0], s[3][1]), x67b = fmaxf(s[3][2], s[3][3]);
        float x = fmaxf(fmaxf(fmaxf(x01a, x01b), fmaxf(x23a, x23b)),
                        fmaxf(fmaxf(x45a, x45b), fmaxf(x67a, x67b)));
        x = fmaxf(x, __shfl_xor(x, 16));
        x = fmaxf(x, __shfl_xor(x, 32));

        // ---- defer-rescale: only pay alpha path when max grew > 8 ----
        if (__any(x - m > 8.0f)) {
            float mn    = fmaxf(m, x);
            float alpha = __builtin_amdgcn_exp2f(m - mn);
            m = mn;
            l *= alpha;
            #pragma unroll
            for (int dt = 0; dt < 4; ++dt) acc[dt] *= alpha;
        }

        // ---- p = exp2(s - m), row sum ----
        float p[4][4], y = 0.0f;
        #pragma unroll
        for (int i = 0; i < 4; ++i)
            #pragma unroll
            for (int r = 0; r < 4; ++r) {
                p[i][r] = __builtin_amdgcn_exp2f(s[i][r] - m);
                y += p[i][r];
            }
        y += __shfl_xor(y, 16);
        y += __shfl_xor(y, 32);
        l += y;

#if HAVE_MFMA16
        // ---- ZERO-SHUFFLE PV: K=16 MFMAs, B = own p[i][0..3] ----
        s16x4 pb[4];
        #pragma unroll
        for (int i = 0; i < 4; ++i) {
            bf16x4 pf;
            #pragma unroll
            for (int b = 0; b < 4; ++b) pf[b] = (__bf16)p[i][b];
            pb[i] = __builtin_bit_cast(s16x4, pf);
        }
        #pragma unroll
        for (int dt = 0; dt < 4; ++dt) {
            const int vrow = dt * 16 + col;
            const int rb   = vrow * 64;
            const int swz  = (vrow & 7) << 4;
            #pragma unroll
            for (int i = 0; i < 4; ++i) {
                const int sb = i >> 1, jt = i & 1;
                bf16x4 vf = *(const bf16x4*)(vtbuf + sb * 4096
                                             + ((rb + jt * 32 + g * 8) ^ swz));
                acc[dt] = __builtin_amdgcn_mfma_f32_16x16x16bf16_1k(
                    __builtin_bit_cast(s16x4, vf), pb[i], acc[dt], 0, 0, 0);
            }
        }
#else
        // ---- fallback: per sub-block pack + 8-shfl permute + K=32 PV ----
        #pragma unroll
        for (int sb = 0; sb < 2; ++sb) {
            unsigned pk00 = pkbf(p[sb * 2][0],     p[sb * 2][1]);
            unsigned pk01 = pkbf(p[sb * 2][2],     p[sb * 2][3]);
            unsigned pk10 = pkbf(p[sb * 2 + 1][0], p[sb * 2 + 1][1]);
            unsigned pk11 = pkbf(p[sb * 2 + 1][2], p[sb * 2 + 1][3]);
            const int srcA = col + ((g & 1) << 5);
            const int srcB = srcA + 16;
            unsigned a00 = __shfl(pk00, srcA), a01 = __shfl(pk01, srcA);
            unsigned a10 = __shfl(pk10, srcA), a11 = __shfl(pk11, srcA);
            unsigned b00 = __shfl(pk00, srcB), b01 = __shfl(pk01, srcB);
            unsigned b10 = __shfl(pk10, srcB), b11 = __shfl(pk11, srcB);
            const bool hi = g >= 2;
            u32x4 pu;
            pu[0] = hi ? a10 : a00;
            pu[1] = hi ? a11 : a01;
            pu[2] = hi ? b10 : b00;
            pu[3] = hi ? b11 : b01;
            bf16x8 pf = __builtin_bit_cast(bf16x8, pu);
            #pragma unroll
            for (int dt = 0; dt < 4; ++dt) {
                const int vrow = dt * 16 + col;
                bf16x8 vf = *(const bf16x8*)(vtbuf + sb * 4096
                                + ((vrow * 64 + g * 16) ^ ((vrow & 7) << 4)));
                acc[dt] = __builtin_amdgcn_mfma_f32_16x16x32_bf16(vf, pf, acc[dt], 0, 0, 0);
            }
        }
#endif

        // ---- write next iteration into the other LDS buffer ----
        if (t + 1 < NT) {
            const int nb = (t + 1) & 1;
            if constexpr (IMG) {
                #pragma unroll
                for (int sb = 0; sb < 2; ++sb)
                    *(f32x4*)(vtdst + nb * 8192 + sb * 4096) = vreg[sb];
            } else {
                #pragma unroll
                for (int sb = 0; sb < 2; ++sb) {
                    bf16x8 kb16, vb16;
                    #pragma unroll
                    for (int b = 0; b < 4; ++b) { kb16[b] = (__bf16)kr[sb][0][b]; kb16[4 + b] = (__bf16)kr[sb][1][b]; }
                    #pragma unroll
                    for (int j = 0; j < 8; ++j) vb16[j] = (__bf16)vv[sb][j];
                    *(bf16x8*)(kdst  + nb * 8192 + sb * 4096) = kb16;
                    *(bf16x8*)(vtdst + nb * 8192 + sb * 4096) = vb16;
                }
            }
        }
        __syncthreads();
    }

    // ---- merge halves (flash combine in O^T layout, base-2 domain) ----
    float* eacc = (float*)smem;            // [w4][q=col 16][d 64]
    float* eml  = (float*)(smem + 16384);  // [w4*16+col]*2

    if (half == 1) {
        #pragma unroll
        for (int dt = 0; dt < 4; ++dt)
            *(f32x4*)(eacc + w4 * 1024 + col * 64 + dt * 16 + g * 4) = acc[dt];
        if (g == 0) {
            eml[(w4 * 16 + col) * 2 + 0] = m;
            eml[(w4 * 16 + col) * 2 + 1] = l;
        }
    }
    __syncthreads();
    if (half == 0) {
        float m2 = eml[(w4 * 16 + col) * 2 + 0];
        float l2 = eml[(w4 * 16 + col) * 2 + 1];
        float mm = fmaxf(m, m2);
        float a1 = __builtin_amdgcn_exp2f(m - mm);
        float a2 = __builtin_amdgcn_exp2f(m2 - mm);
        float inv = 1.0f / (l * a1 + l2 * a2);
        float* orow = out + ((size_t)h * SEQ_LEN + qbase + col) * HEAD_DIM;
        #pragma unroll
        for (int dt = 0; dt < 4; ++dt) {
            f32x4 o2 = *(const f32x4*)(eacc + w4 * 1024 + col * 64 + dt * 16 + g * 4);
            *(f32x4*)(orow + dt * 16 + g * 4) = (acc[dt] * a1 + o2 * a2) * inv;
        }
    }
}

extern "C" void kernel_launch(void* const* d_in, const int* in_sizes, int n_in,
                              void* d_out, int out_size, void* d_ws, size_t ws_size,
                              hipStream_t stream) {
    const float* q = (const float*)d_in[0];
    const float* k = (const float*)d_in[1];
    const float* v = (const float*)d_in[2];
    float* out = (float*)d_out;

    const size_t imgBytes = (size_t)N_HEADS * NTILE_TOT * 4096;   // 4 MiB each

    dim3 grid(SEQ_LEN / 64, N_HEADS, 1);
    if (ws_size >= 2 * imgBytes) {
        char* kimg  = (char*)d_ws;
        char* vtimg = kimg + imgBytes;
        prep_kernel<<<dim3(NTILE_TOT, N_HEADS, 1), dim3(256, 1, 1), 0, stream>>>(
            k, v, kimg, vtimg);
        attn_alibi_kernel<true><<<grid, dim3(512, 1, 1), 0, stream>>>(
            q, k, v, out, kimg, vtimg);
    } else {
        attn_alibi_kernel<false><<<grid, dim3(512, 1, 1), 0, stream>>>(
            q, k, v, out, nullptr, nullptr);
    }
}